// Round 1
// baseline (47546.838 us; speedup 1.0000x reference)
//
#include <hip/hip_runtime.h>

// Problem constants
constexpr int B_ = 8, H_ = 64, W_ = 64, C0 = 16, D_ = 128, K_ = 8192;
constexpr int N_ = B_ * H_ * W_;  // 32768 pixels

__device__ __forceinline__ float gelu_f(float x) {
    return 0.5f * x * (1.0f + erff(x * 0.70710678118654752440f));
}

// ---------------------------------------------------------------------------
// x NCHW [8,16,64,64] -> xt NHWC [8,64,64,16]
__global__ __launch_bounds__(256) void transpose_x_kernel(
    const float* __restrict__ x, float* __restrict__ xt) {
    int i = blockIdx.x * 256 + threadIdx.x;  // over 524288, input-contiguous
    int w = i & 63;
    int h = (i >> 6) & 63;
    int c = (i >> 12) & 15;
    int b = i >> 16;
    xt[(((b << 6) + h) * 64 + w) * 16 + c] = x[i];
}

// w OIHW [co][ci][3][3] -> wt [t=ky*3+kx][ci][co]
__global__ __launch_bounds__(256) void wtrans_kernel(
    const float* __restrict__ w, float* __restrict__ wt, int cin, int total) {
    int i = blockIdx.x * 256 + threadIdx.x;  // i = (t*cin + ci)*128 + co
    if (i >= total) return;
    int co = i & 127;
    int rest = i >> 7;
    int ci = rest % cin;
    int t = rest / cin;
    wt[i] = w[(co * cin + ci) * 9 + t];
}

// ||embed_k||^2
__global__ __launch_bounds__(256) void enorm2_kernel(
    const float* __restrict__ embed, float* __restrict__ e2) {
    int k = blockIdx.x * 256 + threadIdx.x;  // 8192
    const float4* e4 = (const float4*)(embed + (size_t)k * 128);
    float s = 0.0f;
#pragma unroll 8
    for (int i = 0; i < 32; ++i) {
        float4 v = e4[i];
        s += v.x * v.x + v.y * v.y + v.z * v.z + v.w * v.w;
    }
    e2[k] = s;
}

// ---------------------------------------------------------------------------
// 3x3 SAME conv, NHWC in/out, fused bias + GELU.
// Block: 8 consecutive w-pixels in one (b,h) row; 256 threads = 2 pixel-groups
// x 128 cout; each thread accumulates 4 pixels for its cout.
template <int CIN>
__global__ __launch_bounds__(256) void conv3x3_gelu_kernel(
    const float* __restrict__ in,    // NHWC [B,H,W,CIN]
    const float* __restrict__ wt,    // [9*CIN][128]
    const float* __restrict__ bias,  // [128]
    float* __restrict__ out) {       // NHWC [B,H,W,128]
    __shared__ __align__(16) float patch[3 * 10 * CIN];
    int blk = blockIdx.x;            // 4096 = 8 * 64 * 8
    int w0 = (blk & 7) * 8;
    int h = (blk >> 3) & 63;
    int b = blk >> 9;

    constexpr int SLOTS = 3 * 10 * CIN / 4;  // float4 slots
    for (int i = threadIdx.x; i < SLOTS; i += 256) {
        int ci4 = i % (CIN / 4);
        int c = (i / (CIN / 4)) % 10;
        int r = i / (CIN / 4 * 10);
        int hh = h - 1 + r, ww = w0 - 1 + c;
        float4 v = make_float4(0.f, 0.f, 0.f, 0.f);
        if ((unsigned)hh < (unsigned)H_ && (unsigned)ww < (unsigned)W_)
            v = ((const float4*)in)[((b * H_ + hh) * W_ + ww) * (CIN / 4) + ci4];
        ((float4*)patch)[(r * 10 + c) * (CIN / 4) + ci4] = v;
    }
    __syncthreads();

    int co = threadIdx.x & 127;
    int ph = threadIdx.x >> 7;  // 0/1 -> pixels ph*4 .. ph*4+3
    float bv = bias[co];
    float acc[4] = {bv, bv, bv, bv};

#pragma unroll
    for (int ky = 0; ky < 3; ++ky)
#pragma unroll
        for (int kx = 0; kx < 3; ++kx) {
            const float* wrow = wt + ((ky * 3 + kx) * CIN) * 128 + co;
            const float* prow = &patch[(ky * 10 + kx + ph * 4) * CIN];
            for (int ci = 0; ci < CIN; ci += 4) {
                float wa = wrow[(ci + 0) * 128];
                float wb = wrow[(ci + 1) * 128];
                float wc = wrow[(ci + 2) * 128];
                float wd = wrow[(ci + 3) * 128];
#pragma unroll
                for (int j = 0; j < 4; ++j) {
                    float4 p = *(const float4*)&prow[j * CIN + ci];
                    acc[j] += p.x * wa + p.y * wb + p.z * wc + p.w * wd;
                }
            }
        }

    int pixbase = (b * H_ + h) * W_ + w0 + ph * 4;
#pragma unroll
    for (int j = 0; j < 4; ++j)
        out[(size_t)(pixbase + j) * 128 + co] = gelu_f(acc[j]);
}

// ---------------------------------------------------------------------------
// VQ: per block 64 pixels x all 8192 codes; fused GEMM + running argmin.
// score = ||e||^2 - 2 f.e  (||f||^2 dropped, same argmin). Tie -> smaller idx.
__global__ __launch_bounds__(256) void vq_argmin_kernel(
    const float* __restrict__ flat,   // [N][128]
    const float* __restrict__ embed,  // [K][128]
    const float* __restrict__ e2,     // [K]
    int* __restrict__ out_idx) {      // [N]
    constexpr int TM = 64, TN = 128, LDA = 136, LDB = 36;
    __shared__ __align__(16) float As[TM * LDA];
    __shared__ __align__(16) float Bs[TN * LDB];
    __shared__ float e2s[TN];
    int m0 = blockIdx.x * TM;
    int tid = threadIdx.x;

    // stage A tile: 64 pixels x 128 d
    for (int i = tid; i < TM * 32; i += 256) {
        int p = i >> 5, dq = i & 31;
        float4 v = ((const float4*)flat)[(m0 + p) * 32 + dq];
        *(float4*)&As[p * LDA + dq * 4] = v;
    }

    int ty = tid >> 4;  // 0..15: pixels {ty, ty+16, ty+32, ty+48}
    int tx = tid & 15;  // codes  {tx, tx+16, ..., tx+112} within tile
    float best[4];
    int bidx[4];
#pragma unroll
    for (int j = 0; j < 4; ++j) {
        best[j] = 3.4e38f;
        bidx[j] = 0;
    }

    for (int t = 0; t < K_ / TN; ++t) {
        int cbase = t * TN;
        __syncthreads();  // prior-tile LDS reads done
        if (tid < TN) e2s[tid] = e2[cbase + tid];
        float acc[4][8];
#pragma unroll
        for (int j = 0; j < 4; ++j)
#pragma unroll
            for (int c = 0; c < 8; ++c) acc[j][c] = 0.f;

        for (int ch = 0; ch < 4; ++ch) {  // d-chunks of 32
            __syncthreads();
            for (int i = tid; i < TN * 8; i += 256) {
                int c = i >> 3, dq = i & 7;
                float4 v = ((const float4*)embed)[(cbase + c) * 32 + ch * 8 + dq];
                *(float4*)&Bs[c * LDB + dq * 4] = v;
            }
            __syncthreads();
#pragma unroll
            for (int dq = 0; dq < 8; ++dq) {
                float4 a[4];
#pragma unroll
                for (int j = 0; j < 4; ++j)
                    a[j] = *(const float4*)&As[(j * 16 + ty) * LDA + ch * 32 + dq * 4];
#pragma unroll
                for (int c = 0; c < 8; ++c) {
                    float4 bv = *(const float4*)&Bs[(c * 16 + tx) * LDB + dq * 4];
#pragma unroll
                    for (int j = 0; j < 4; ++j)
                        acc[j][c] += a[j].x * bv.x + a[j].y * bv.y +
                                     a[j].z * bv.z + a[j].w * bv.w;
                }
            }
        }
#pragma unroll
        for (int c = 0; c < 8; ++c) {
            int lc = c * 16 + tx;
            int gcode = cbase + lc;
            float se = e2s[lc];
#pragma unroll
            for (int j = 0; j < 4; ++j) {
                float s = se - 2.0f * acc[j][c];
                if (s < best[j] || (s == best[j] && gcode < bidx[j])) {
                    best[j] = s;
                    bidx[j] = gcode;
                }
            }
        }
    }
    // reduce across the 16 tx lanes of each pixel
#pragma unroll
    for (int j = 0; j < 4; ++j) {
        float s = best[j];
        int bi = bidx[j];
        for (int off = 8; off > 0; off >>= 1) {
            float os = __shfl_down(s, off, 16);
            int oi = __shfl_down(bi, off, 16);
            if (os < s || (os == s && oi < bi)) {
                s = os;
                bi = oi;
            }
        }
        if (tx == 0) out_idx[m0 + j * 16 + ty] = bi;
    }
}

// ---------------------------------------------------------------------------
__global__ __launch_bounds__(256) void gather_kernel(
    const float* __restrict__ embed, const int* __restrict__ idx,
    float* __restrict__ q) {
    int n = blockIdx.x * 8 + (threadIdx.x >> 5);
    int dq = threadIdx.x & 31;
    int k = idx[n];
    ((float4*)q)[n * 32 + dq] = ((const float4*)embed)[k * 32 + dq];
}

// 1x1 conv (128->16) + sigmoid, NHWC in -> NCHW out
__global__ __launch_bounds__(256) void dec2_kernel(
    const float* __restrict__ y,   // NHWC [B,H,W,128]
    const float* __restrict__ w2,  // [16][128]
    const float* __restrict__ b2,  // [16]
    float* __restrict__ out) {     // NCHW [B,16,H,W]
    __shared__ float ys[64 * 130];
    __shared__ float ws[16 * 128];
    int blk = blockIdx.x;  // 512 = B*H
    int h = blk & 63;
    int b = blk >> 6;
    const float* yrow = y + (size_t)((b * H_ + h) * W_) * 128;
    for (int i = threadIdx.x; i < 64 * 64; i += 256) {
        int w = i >> 6, dh = i & 63;
        *(float2*)&ys[w * 130 + dh * 2] = *(const float2*)&yrow[w * 128 + dh * 2];
    }
    for (int i = threadIdx.x; i < 2048; i += 256) ws[i] = w2[i];
    __syncthreads();

    int w = threadIdx.x & 63;
    int c0 = (threadIdx.x >> 6) * 4;  // 0,4,8,12
    float acc[4] = {b2[c0], b2[c0 + 1], b2[c0 + 2], b2[c0 + 3]};
    for (int ci = 0; ci < 128; ci += 2) {
        float2 yv = *(const float2*)&ys[w * 130 + ci];
#pragma unroll
        for (int jc = 0; jc < 4; ++jc) {
            float2 wv = *(const float2*)&ws[(c0 + jc) * 128 + ci];
            acc[jc] += yv.x * wv.x + yv.y * wv.y;
        }
    }
#pragma unroll
    for (int jc = 0; jc < 4; ++jc) {
        float v = 1.0f / (1.0f + expf(-acc[jc]));
        out[(((size_t)b * 16 + c0 + jc) * H_ + h) * W_ + w] = v;
    }
}

// ---------------------------------------------------------------------------
extern "C" void kernel_launch(void* const* d_in, const int* in_sizes, int n_in,
                              void* d_out, int out_size, void* d_ws,
                              size_t ws_size, hipStream_t stream) {
    const float* x = (const float*)d_in[0];
    const float* ew1 = (const float*)d_in[1];
    const float* eb1 = (const float*)d_in[2];
    const float* ew2 = (const float*)d_in[3];
    const float* eb2 = (const float*)d_in[4];
    const float* embed = (const float*)d_in[5];
    const float* dw1 = (const float*)d_in[6];
    const float* db1 = (const float*)d_in[7];
    const float* dw2 = (const float*)d_in[8];
    const float* db2 = (const float*)d_in[9];
    float* out = (float*)d_out;

    float* xt = (float*)d_ws;            // 524288 floats
    float* bufA = xt + 524288;           // 4194304 floats
    float* bufB = bufA + 4194304;        // 4194304 floats
    float* wt1 = bufB + 4194304;         // 18432
    float* wt2 = wt1 + 18432;            // 147456
    float* wt3 = wt2 + 147456;           // 147456
    float* e2 = wt3 + 147456;            // 8192
    int* idx = (int*)(e2 + 8192);        // 32768 ints

    transpose_x_kernel<<<2048, 256, 0, stream>>>(x, xt);
    wtrans_kernel<<<72, 256, 0, stream>>>(ew1, wt1, 16, 9 * 16 * 128);
    wtrans_kernel<<<576, 256, 0, stream>>>(ew2, wt2, 128, 9 * 128 * 128);
    wtrans_kernel<<<576, 256, 0, stream>>>(dw1, wt3, 128, 9 * 128 * 128);
    enorm2_kernel<<<32, 256, 0, stream>>>(embed, e2);

    conv3x3_gelu_kernel<16><<<4096, 256, 0, stream>>>(xt, wt1, eb1, bufA);
    conv3x3_gelu_kernel<128><<<4096, 256, 0, stream>>>(bufA, wt2, eb2, bufB);
    vq_argmin_kernel<<<512, 256, 0, stream>>>(bufB, embed, e2, idx);
    gather_kernel<<<4096, 256, 0, stream>>>(embed, idx, bufA);
    conv3x3_gelu_kernel<128><<<4096, 256, 0, stream>>>(bufA, wt3, db1, bufB);
    dec2_kernel<<<512, 256, 0, stream>>>(bufB, dw2, db2, out);
}

// Round 2
// 3149.698 us; speedup vs baseline: 15.0957x; 15.0957x over previous
//
#include <hip/hip_runtime.h>

// Problem constants
constexpr int B_ = 8, H_ = 64, W_ = 64, C0 = 16, D_ = 128, K_ = 8192;
constexpr int N_ = B_ * H_ * W_;  // 32768 pixels

__device__ __forceinline__ float gelu_f(float x) {
    return 0.5f * x * (1.0f + erff(x * 0.70710678118654752440f));
}

// ---------------------------------------------------------------------------
// x NCHW [8,16,64,64] -> xt NHWC [8,64,64,16]
__global__ __launch_bounds__(256) void transpose_x_kernel(
    const float* __restrict__ x, float* __restrict__ xt) {
    int i = blockIdx.x * 256 + threadIdx.x;  // over 524288, input-contiguous
    int w = i & 63;
    int h = (i >> 6) & 63;
    int c = (i >> 12) & 15;
    int b = i >> 16;
    xt[(((b << 6) + h) * 64 + w) * 16 + c] = x[i];
}

// w OIHW [co][ci][3][3] -> wt [t=ky*3+kx][ci][co]
__global__ __launch_bounds__(256) void wtrans_kernel(
    const float* __restrict__ w, float* __restrict__ wt, int cin, int total) {
    int i = blockIdx.x * 256 + threadIdx.x;  // i = (t*cin + ci)*128 + co
    if (i >= total) return;
    int co = i & 127;
    int rest = i >> 7;
    int ci = rest % cin;
    int t = rest / cin;
    wt[i] = w[(co * cin + ci) * 9 + t];
}

// ||embed_k||^2
__global__ __launch_bounds__(256) void enorm2_kernel(
    const float* __restrict__ embed, float* __restrict__ e2) {
    int k = blockIdx.x * 256 + threadIdx.x;  // 8192
    const float4* e4 = (const float4*)(embed + (size_t)k * 128);
    float s = 0.0f;
#pragma unroll 8
    for (int i = 0; i < 32; ++i) {
        float4 v = e4[i];
        s += v.x * v.x + v.y * v.y + v.z * v.z + v.w * v.w;
    }
    e2[k] = s;
}

// ---------------------------------------------------------------------------
// 3x3 SAME conv, NHWC in/out, fused bias + GELU.
// Block: 16 consecutive w-pixels in one (b,h) row; 256 threads =
// 2 pixel-groups x 128 cout; each thread accumulates 8 pixels for its cout.
// ci loop is `#pragma unroll 1` — the round-1 version let LLVM unroll the
// whole 9x32 nest, hoist ~1100 global weight loads, and spill 11 KB/thread.
template <int CIN>
__global__ __launch_bounds__(256) void conv3x3_gelu_kernel(
    const float* __restrict__ in,    // NHWC [B,H,W,CIN]
    const float* __restrict__ wt,    // [9*CIN][128]
    const float* __restrict__ bias,  // [128]
    float* __restrict__ out) {       // NHWC [B,H,W,128]
    constexpr int CIN4 = CIN / 4;
    __shared__ __align__(16) float patch[3 * 18 * CIN];
    int blk = blockIdx.x;  // 2048 = 8 * 64 * 4
    int w0 = (blk & 3) * 16;
    int h = (blk >> 2) & 63;
    int b = blk >> 8;

    constexpr int SLOTS = 3 * 18 * CIN4;  // float4 slots
    for (int i = threadIdx.x; i < SLOTS; i += 256) {
        int ci4 = i % CIN4;
        int c = (i / CIN4) % 18;
        int r = i / (CIN4 * 18);
        int hh = h - 1 + r, ww = w0 - 1 + c;
        float4 v = make_float4(0.f, 0.f, 0.f, 0.f);
        if ((unsigned)hh < (unsigned)H_ && (unsigned)ww < (unsigned)W_)
            v = ((const float4*)in)[((b * H_ + hh) * W_ + ww) * CIN4 + ci4];
        ((float4*)patch)[(r * 18 + c) * CIN4 + ci4] = v;
    }
    __syncthreads();

    int co = threadIdx.x & 127;
    int ph = threadIdx.x >> 7;  // 0/1 -> pixels ph*8 .. ph*8+7
    float bv = bias[co];
    float acc[8];
#pragma unroll
    for (int j = 0; j < 8; ++j) acc[j] = bv;

#pragma unroll
    for (int ky = 0; ky < 3; ++ky)
#pragma unroll
        for (int kx = 0; kx < 3; ++kx) {
            const float* wrow = wt + ((ky * 3 + kx) * CIN) * 128 + co;
            const float* prow = &patch[(ky * 18 + kx + ph * 8) * CIN];
#pragma unroll 1
            for (int ci = 0; ci < CIN; ci += 4) {
                float wa = wrow[(ci + 0) * 128];
                float wb = wrow[(ci + 1) * 128];
                float wc = wrow[(ci + 2) * 128];
                float wd = wrow[(ci + 3) * 128];
#pragma unroll
                for (int j = 0; j < 8; ++j) {
                    float4 p = *(const float4*)&prow[j * CIN + ci];
                    acc[j] += p.x * wa + p.y * wb + p.z * wc + p.w * wd;
                }
            }
        }

    int pixbase = (b * H_ + h) * W_ + w0 + ph * 8;
#pragma unroll
    for (int j = 0; j < 8; ++j)
        out[(size_t)(pixbase + j) * 128 + co] = gelu_f(acc[j]);
}

// ---------------------------------------------------------------------------
// VQ: per block 64 pixels x all 8192 codes; fused GEMM + running argmin.
// score = ||e||^2 - 2 f.e  (||f||^2 dropped, same argmin). Tie -> smaller idx.
__global__ __launch_bounds__(256) void vq_argmin_kernel(
    const float* __restrict__ flat,   // [N][128]
    const float* __restrict__ embed,  // [K][128]
    const float* __restrict__ e2,     // [K]
    int* __restrict__ out_idx) {      // [N]
    constexpr int TM = 64, TN = 128, LDA = 136, LDB = 36;
    __shared__ __align__(16) float As[TM * LDA];
    __shared__ __align__(16) float Bs[TN * LDB];
    __shared__ float e2s[TN];
    int m0 = blockIdx.x * TM;
    int tid = threadIdx.x;

    // stage A tile: 64 pixels x 128 d
    for (int i = tid; i < TM * 32; i += 256) {
        int p = i >> 5, dq = i & 31;
        float4 v = ((const float4*)flat)[(m0 + p) * 32 + dq];
        *(float4*)&As[p * LDA + dq * 4] = v;
    }

    int ty = tid >> 4;  // 0..15: pixels {ty, ty+16, ty+32, ty+48}
    int tx = tid & 15;  // codes  {tx, tx+16, ..., tx+112} within tile
    float best[4];
    int bidx[4];
#pragma unroll
    for (int j = 0; j < 4; ++j) {
        best[j] = 3.4e38f;
        bidx[j] = 0;
    }

    for (int t = 0; t < K_ / TN; ++t) {
        int cbase = t * TN;
        __syncthreads();  // prior-tile LDS reads done
        if (tid < TN) e2s[tid] = e2[cbase + tid];
        float acc[4][8];
#pragma unroll
        for (int j = 0; j < 4; ++j)
#pragma unroll
            for (int c = 0; c < 8; ++c) acc[j][c] = 0.f;

        for (int ch = 0; ch < 4; ++ch) {  // d-chunks of 32
            __syncthreads();
            for (int i = tid; i < TN * 8; i += 256) {
                int c = i >> 3, dq = i & 7;
                float4 v = ((const float4*)embed)[(cbase + c) * 32 + ch * 8 + dq];
                *(float4*)&Bs[c * LDB + dq * 4] = v;
            }
            __syncthreads();
#pragma unroll
            for (int dq = 0; dq < 8; ++dq) {
                float4 a[4];
#pragma unroll
                for (int j = 0; j < 4; ++j)
                    a[j] = *(const float4*)&As[(j * 16 + ty) * LDA + ch * 32 + dq * 4];
#pragma unroll
                for (int c = 0; c < 8; ++c) {
                    float4 bv = *(const float4*)&Bs[(c * 16 + tx) * LDB + dq * 4];
#pragma unroll
                    for (int j = 0; j < 4; ++j)
                        acc[j][c] += a[j].x * bv.x + a[j].y * bv.y +
                                     a[j].z * bv.z + a[j].w * bv.w;
                }
            }
        }
#pragma unroll
        for (int c = 0; c < 8; ++c) {
            int lc = c * 16 + tx;
            int gcode = cbase + lc;
            float se = e2s[lc];
#pragma unroll
            for (int j = 0; j < 4; ++j) {
                float s = se - 2.0f * acc[j][c];
                if (s < best[j] || (s == best[j] && gcode < bidx[j])) {
                    best[j] = s;
                    bidx[j] = gcode;
                }
            }
        }
    }
    // reduce across the 16 tx lanes of each pixel
#pragma unroll
    for (int j = 0; j < 4; ++j) {
        float s = best[j];
        int bi = bidx[j];
        for (int off = 8; off > 0; off >>= 1) {
            float os = __shfl_down(s, off, 16);
            int oi = __shfl_down(bi, off, 16);
            if (os < s || (os == s && oi < bi)) {
                s = os;
                bi = oi;
            }
        }
        if (tx == 0) out_idx[m0 + j * 16 + ty] = bi;
    }
}

// ---------------------------------------------------------------------------
__global__ __launch_bounds__(256) void gather_kernel(
    const float* __restrict__ embed, const int* __restrict__ idx,
    float* __restrict__ q) {
    int n = blockIdx.x * 8 + (threadIdx.x >> 5);
    int dq = threadIdx.x & 31;
    int k = idx[n];
    ((float4*)q)[n * 32 + dq] = ((const float4*)embed)[k * 32 + dq];
}

// 1x1 conv (128->16) + sigmoid, NHWC in -> NCHW out
__global__ __launch_bounds__(256) void dec2_kernel(
    const float* __restrict__ y,   // NHWC [B,H,W,128]
    const float* __restrict__ w2,  // [16][128]
    const float* __restrict__ b2,  // [16]
    float* __restrict__ out) {     // NCHW [B,16,H,W]
    __shared__ float ys[64 * 130];
    __shared__ float ws[16 * 128];
    int blk = blockIdx.x;  // 512 = B*H
    int h = blk & 63;
    int b = blk >> 6;
    const float* yrow = y + (size_t)((b * H_ + h) * W_) * 128;
    for (int i = threadIdx.x; i < 64 * 64; i += 256) {
        int w = i >> 6, dh = i & 63;
        *(float2*)&ys[w * 130 + dh * 2] = *(const float2*)&yrow[w * 128 + dh * 2];
    }
    for (int i = threadIdx.x; i < 2048; i += 256) ws[i] = w2[i];
    __syncthreads();

    int w = threadIdx.x & 63;
    int c0 = (threadIdx.x >> 6) * 4;  // 0,4,8,12
    float acc[4] = {b2[c0], b2[c0 + 1], b2[c0 + 2], b2[c0 + 3]};
#pragma unroll 1
    for (int ci = 0; ci < 128; ci += 2) {
        float2 yv = *(const float2*)&ys[w * 130 + ci];
#pragma unroll
        for (int jc = 0; jc < 4; ++jc) {
            float2 wv = *(const float2*)&ws[(c0 + jc) * 128 + ci];
            acc[jc] += yv.x * wv.x + yv.y * wv.y;
        }
    }
#pragma unroll
    for (int jc = 0; jc < 4; ++jc) {
        float v = 1.0f / (1.0f + expf(-acc[jc]));
        out[(((size_t)b * 16 + c0 + jc) * H_ + h) * W_ + w] = v;
    }
}

// ---------------------------------------------------------------------------
extern "C" void kernel_launch(void* const* d_in, const int* in_sizes, int n_in,
                              void* d_out, int out_size, void* d_ws,
                              size_t ws_size, hipStream_t stream) {
    const float* x = (const float*)d_in[0];
    const float* ew1 = (const float*)d_in[1];
    const float* eb1 = (const float*)d_in[2];
    const float* ew2 = (const float*)d_in[3];
    const float* eb2 = (const float*)d_in[4];
    const float* embed = (const float*)d_in[5];
    const float* dw1 = (const float*)d_in[6];
    const float* db1 = (const float*)d_in[7];
    const float* dw2 = (const float*)d_in[8];
    const float* db2 = (const float*)d_in[9];
    float* out = (float*)d_out;

    float* xt = (float*)d_ws;            // 524288 floats
    float* bufA = xt + 524288;           // 4194304 floats
    float* bufB = bufA + 4194304;        // 4194304 floats
    float* wt1 = bufB + 4194304;         // 18432
    float* wt2 = wt1 + 18432;            // 147456
    float* wt3 = wt2 + 147456;           // 147456
    float* e2 = wt3 + 147456;            // 8192
    int* idx = (int*)(e2 + 8192);        // 32768 ints

    transpose_x_kernel<<<2048, 256, 0, stream>>>(x, xt);
    wtrans_kernel<<<72, 256, 0, stream>>>(ew1, wt1, 16, 9 * 16 * 128);
    wtrans_kernel<<<576, 256, 0, stream>>>(ew2, wt2, 128, 9 * 128 * 128);
    wtrans_kernel<<<576, 256, 0, stream>>>(dw1, wt3, 128, 9 * 128 * 128);
    enorm2_kernel<<<32, 256, 0, stream>>>(embed, e2);

    conv3x3_gelu_kernel<16><<<2048, 256, 0, stream>>>(xt, wt1, eb1, bufA);
    conv3x3_gelu_kernel<128><<<2048, 256, 0, stream>>>(bufA, wt2, eb2, bufB);
    vq_argmin_kernel<<<512, 256, 0, stream>>>(bufB, embed, e2, idx);
    gather_kernel<<<4096, 256, 0, stream>>>(embed, idx, bufA);
    conv3x3_gelu_kernel<128><<<2048, 256, 0, stream>>>(bufA, wt3, db1, bufB);
    dec2_kernel<<<512, 256, 0, stream>>>(bufB, dw2, db2, out);
}

// Round 3
// 682.961 us; speedup vs baseline: 69.6186x; 4.6118x over previous
//
#include <hip/hip_runtime.h>

// Problem constants
constexpr int B_ = 8, H_ = 64, W_ = 64, C0 = 16, D_ = 128, K_ = 8192;
constexpr int N_ = B_ * H_ * W_;  // 32768 pixels

typedef __attribute__((ext_vector_type(8))) short short8;   // 8 bf16
typedef __attribute__((ext_vector_type(4))) float f32x4;    // MFMA C/D

__device__ __forceinline__ float gelu_f(float x) {
    return 0.5f * x * (1.0f + erff(x * 0.70710678118654752440f));
}

__device__ __forceinline__ unsigned short f2bf(float f) {  // RNE f32->bf16
    unsigned u = __float_as_uint(f);
    u += 0x7fffu + ((u >> 16) & 1u);
    return (unsigned short)(u >> 16);
}

// ---------------------------------------------------------------------------
// x NCHW [8,16,64,64] -> xt NHWC [8,64,64,16]
__global__ __launch_bounds__(256) void transpose_x_kernel(
    const float* __restrict__ x, float* __restrict__ xt) {
    int i = blockIdx.x * 256 + threadIdx.x;
    int w = i & 63;
    int h = (i >> 6) & 63;
    int c = (i >> 12) & 15;
    int b = i >> 16;
    xt[(((b << 6) + h) * 64 + w) * 16 + c] = x[i];
}

// w OIHW [co][ci][3][3] -> wt [t=ky*3+kx][ci][co]
__global__ __launch_bounds__(256) void wtrans_kernel(
    const float* __restrict__ w, float* __restrict__ wt, int cin, int total) {
    int i = blockIdx.x * 256 + threadIdx.x;
    if (i >= total) return;
    int co = i & 127;
    int rest = i >> 7;
    int ci = rest % cin;
    int t = rest / cin;
    wt[i] = w[(co * cin + ci) * 9 + t];
}

// ||embed_k||^2 (fp32, exact)
__global__ __launch_bounds__(256) void enorm2_kernel(
    const float* __restrict__ embed, float* __restrict__ e2) {
    int k = blockIdx.x * 256 + threadIdx.x;
    const float4* e4 = (const float4*)(embed + (size_t)k * 128);
    float s = 0.0f;
#pragma unroll 8
    for (int i = 0; i < 32; ++i) {
        float4 v = e4[i];
        s += v.x * v.x + v.y * v.y + v.z * v.z + v.w * v.w;
    }
    e2[k] = s;
}

// fp32 -> bf16 cast, 4 elems/thread
__global__ __launch_bounds__(256) void cast_bf16_kernel(
    const float* __restrict__ in, unsigned short* __restrict__ out) {
    int i = blockIdx.x * 256 + threadIdx.x;
    float4 v = ((const float4*)in)[i];
    uint2 o;
    o.x = (unsigned)f2bf(v.x) | ((unsigned)f2bf(v.y) << 16);
    o.y = (unsigned)f2bf(v.z) | ((unsigned)f2bf(v.w) << 16);
    ((uint2*)out)[i] = o;
}

// ---------------------------------------------------------------------------
// 3x3 SAME conv, NHWC in/out, fused bias + GELU. Optional bf16 output.
template <int CIN, bool OUT_BF16>
__global__ __launch_bounds__(256) void conv3x3_gelu_kernel(
    const float* __restrict__ in,    // NHWC [B,H,W,CIN]
    const float* __restrict__ wt,    // [9*CIN][128]
    const float* __restrict__ bias,  // [128]
    void* __restrict__ out_) {       // NHWC [B,H,W,128] f32 or bf16
    constexpr int CIN4 = CIN / 4;
    __shared__ __align__(16) float patch[3 * 18 * CIN];
    int blk = blockIdx.x;  // 2048 = 8 * 64 * 4
    int w0 = (blk & 3) * 16;
    int h = (blk >> 2) & 63;
    int b = blk >> 8;

    constexpr int SLOTS = 3 * 18 * CIN4;
    for (int i = threadIdx.x; i < SLOTS; i += 256) {
        int ci4 = i % CIN4;
        int c = (i / CIN4) % 18;
        int r = i / (CIN4 * 18);
        int hh = h - 1 + r, ww = w0 - 1 + c;
        float4 v = make_float4(0.f, 0.f, 0.f, 0.f);
        if ((unsigned)hh < (unsigned)H_ && (unsigned)ww < (unsigned)W_)
            v = ((const float4*)in)[((b * H_ + hh) * W_ + ww) * CIN4 + ci4];
        ((float4*)patch)[(r * 18 + c) * CIN4 + ci4] = v;
    }
    __syncthreads();

    int co = threadIdx.x & 127;
    int ph = threadIdx.x >> 7;
    float bv = bias[co];
    float acc[8];
#pragma unroll
    for (int j = 0; j < 8; ++j) acc[j] = bv;

#pragma unroll
    for (int ky = 0; ky < 3; ++ky)
#pragma unroll
        for (int kx = 0; kx < 3; ++kx) {
            const float* wrow = wt + ((ky * 3 + kx) * CIN) * 128 + co;
            const float* prow = &patch[(ky * 18 + kx + ph * 8) * CIN];
#pragma unroll 1
            for (int ci = 0; ci < CIN; ci += 4) {
                float wa = wrow[(ci + 0) * 128];
                float wb = wrow[(ci + 1) * 128];
                float wc = wrow[(ci + 2) * 128];
                float wd = wrow[(ci + 3) * 128];
#pragma unroll
                for (int j = 0; j < 8; ++j) {
                    float4 p = *(const float4*)&prow[j * CIN + ci];
                    acc[j] += p.x * wa + p.y * wb + p.z * wc + p.w * wd;
                }
            }
        }

    int pixbase = (b * H_ + h) * W_ + w0 + ph * 8;
#pragma unroll
    for (int j = 0; j < 8; ++j) {
        float g = gelu_f(acc[j]);
        if (OUT_BF16)
            ((unsigned short*)out_)[(size_t)(pixbase + j) * 128 + co] = f2bf(g);
        else
            ((float*)out_)[(size_t)(pixbase + j) * 128 + co] = g;
    }
}

// ---------------------------------------------------------------------------
// VQ via bf16 MFMA. Block = 4 waves; block tile 64 pixels x 256 codes/iter,
// 32 iters over K=8192 codes. Wave w owns codes [cbase+w*64, +64).
// A-frags (64 pixels x K=128 contraction) live in registers for all iters.
// score = ||e||^2 - 2 f.e ; running argmin with strict < (= first-min since
// code order ascending); final cross-wave merge via LDS (s,idx) lex-min.
__global__ __launch_bounds__(256, 2) void vq_mfma_kernel(
    const unsigned short* __restrict__ flatbf,  // [N][128] bf16
    const unsigned short* __restrict__ embbf,   // [K][128] bf16
    const float* __restrict__ e2,               // [K] fp32
    int* __restrict__ out_idx) {                // [N]
    constexpr int LDB = 136;  // 128 + 8 shorts pad: bank-balanced b128 reads
    __shared__ unsigned short Bs[256 * LDB];  // 68 KB
    __shared__ float e2s[256];
    int tid = threadIdx.x;
    int w = tid >> 6, lane = tid & 63;
    int r = lane & 15, q = lane >> 4;
    int m0 = blockIdx.x * 64;

    // ---- stage A: 64 pixels x 128 dims into Bs rows 0..63, then to regs
#pragma unroll
    for (int j = 0; j < 4; ++j) {
        int row = j * 16 + (tid >> 4), col = tid & 15;
        float4 v = *(const float4*)(flatbf + (size_t)(m0 + row) * 128 + col * 8);
        *(float4*)(Bs + row * LDB + col * 8) = v;
    }
    __syncthreads();
    short8 afr[4][4];  // [ms][k]
#pragma unroll
    for (int ms = 0; ms < 4; ++ms)
#pragma unroll
        for (int k = 0; k < 4; ++k)
            afr[ms][k] =
                *(const short8*)(Bs + (ms * 16 + r) * LDB + k * 32 + q * 8);
    __syncthreads();  // A-frag reads done before B staging overwrites

    float best[4][4];
    int bidx[4][4];
#pragma unroll
    for (int ms = 0; ms < 4; ++ms)
#pragma unroll
        for (int rg = 0; rg < 4; ++rg) {
            best[ms][rg] = 3.4e38f;
            bidx[ms][rg] = 0;
        }

    for (int it = 0; it < 32; ++it) {
        int cbase = it << 8;
        // stage B: 256 codes x 128 dims (coalesced 1KB/wave-instr)
#pragma unroll 4
        for (int j = 0; j < 16; ++j) {
            int row = j * 16 + (tid >> 4), col = tid & 15;
            float4 v =
                *(const float4*)(embbf + (size_t)(cbase + row) * 128 + col * 8);
            *(float4*)(Bs + row * LDB + col * 8) = v;
        }
        e2s[tid] = e2[cbase + tid];
        __syncthreads();

        f32x4 acc[4][4];  // [ms][ns]
#pragma unroll
        for (int ms = 0; ms < 4; ++ms)
#pragma unroll
            for (int ns = 0; ns < 4; ++ns) acc[ms][ns] = (f32x4){0.f, 0.f, 0.f, 0.f};

#pragma unroll
        for (int k = 0; k < 4; ++k) {
            short8 bfr[4];
#pragma unroll
            for (int ns = 0; ns < 4; ++ns)
                bfr[ns] = *(const short8*)(Bs + (w * 64 + ns * 16 + r) * LDB +
                                           k * 32 + q * 8);
#pragma unroll
            for (int ms = 0; ms < 4; ++ms)
#pragma unroll
                for (int ns = 0; ns < 4; ++ns)
                    acc[ms][ns] = __builtin_amdgcn_mfma_f32_16x16x32_bf16(
                        afr[ms][k], bfr[ns], acc[ms][ns], 0, 0, 0);
        }

        // epilogue: running argmin (ns ascending => code ascending)
#pragma unroll
        for (int ns = 0; ns < 4; ++ns) {
            float e2v = e2s[w * 64 + ns * 16 + r];
            int code = cbase + w * 64 + ns * 16 + r;
#pragma unroll
            for (int ms = 0; ms < 4; ++ms)
#pragma unroll
                for (int rg = 0; rg < 4; ++rg) {
                    float s = fmaf(-2.0f, acc[ms][ns][rg], e2v);
                    if (s < best[ms][rg]) {
                        best[ms][rg] = s;
                        bidx[ms][rg] = code;
                    }
                }
        }
        __syncthreads();  // epilogue frag reads done before next staging
    }

    // ---- merge 64 candidates/pixel (16 lanes x 4 waves) via LDS
    float* sred = (float*)Bs;              // [64][65]
    int* ired = (int*)(Bs + 8320);         // byte 16640, [64][65]
    int cand = w * 16 + r;
#pragma unroll
    for (int ms = 0; ms < 4; ++ms)
#pragma unroll
        for (int rg = 0; rg < 4; ++rg) {
            int pixel = ms * 16 + q * 4 + rg;
            sred[pixel * 65 + cand] = best[ms][rg];
            ired[pixel * 65 + cand] = bidx[ms][rg];
        }
    __syncthreads();
    if (tid < 64) {
        float bs = sred[tid * 65];
        int bi = ired[tid * 65];
        for (int c = 1; c < 64; ++c) {
            float s = sred[tid * 65 + c];
            int i2 = ired[tid * 65 + c];
            if (s < bs || (s == bs && i2 < bi)) {
                bs = s;
                bi = i2;
            }
        }
        out_idx[m0 + tid] = bi;
    }
}

// ---------------------------------------------------------------------------
__global__ __launch_bounds__(256) void gather_kernel(
    const float* __restrict__ embed, const int* __restrict__ idx,
    float* __restrict__ q) {
    int n = blockIdx.x * 8 + (threadIdx.x >> 5);
    int dq = threadIdx.x & 31;
    int k = idx[n];
    ((float4*)q)[n * 32 + dq] = ((const float4*)embed)[k * 32 + dq];
}

// 1x1 conv (128->16) + sigmoid, NHWC in -> NCHW out
__global__ __launch_bounds__(256) void dec2_kernel(
    const float* __restrict__ y, const float* __restrict__ w2,
    const float* __restrict__ b2, float* __restrict__ out) {
    __shared__ float ys[64 * 130];
    __shared__ float ws[16 * 128];
    int blk = blockIdx.x;  // 512 = B*H
    int h = blk & 63;
    int b = blk >> 6;
    const float* yrow = y + (size_t)((b * H_ + h) * W_) * 128;
    for (int i = threadIdx.x; i < 64 * 64; i += 256) {
        int w = i >> 6, dh = i & 63;
        *(float2*)&ys[w * 130 + dh * 2] = *(const float2*)&yrow[w * 128 + dh * 2];
    }
    for (int i = threadIdx.x; i < 2048; i += 256) ws[i] = w2[i];
    __syncthreads();

    int w = threadIdx.x & 63;
    int c0 = (threadIdx.x >> 6) * 4;
    float acc[4] = {b2[c0], b2[c0 + 1], b2[c0 + 2], b2[c0 + 3]};
#pragma unroll 1
    for (int ci = 0; ci < 128; ci += 2) {
        float2 yv = *(const float2*)&ys[w * 130 + ci];
#pragma unroll
        for (int jc = 0; jc < 4; ++jc) {
            float2 wv = *(const float2*)&ws[(c0 + jc) * 128 + ci];
            acc[jc] += yv.x * wv.x + yv.y * wv.y;
        }
    }
#pragma unroll
    for (int jc = 0; jc < 4; ++jc) {
        float v = 1.0f / (1.0f + expf(-acc[jc]));
        out[(((size_t)b * 16 + c0 + jc) * H_ + h) * W_ + w] = v;
    }
}

// ---------------------------------------------------------------------------
extern "C" void kernel_launch(void* const* d_in, const int* in_sizes, int n_in,
                              void* d_out, int out_size, void* d_ws,
                              size_t ws_size, hipStream_t stream) {
    const float* x = (const float*)d_in[0];
    const float* ew1 = (const float*)d_in[1];
    const float* eb1 = (const float*)d_in[2];
    const float* ew2 = (const float*)d_in[3];
    const float* eb2 = (const float*)d_in[4];
    const float* embed = (const float*)d_in[5];
    const float* dw1 = (const float*)d_in[6];
    const float* db1 = (const float*)d_in[7];
    const float* dw2 = (const float*)d_in[8];
    const float* db2 = (const float*)d_in[9];
    float* out = (float*)d_out;

    float* xt = (float*)d_ws;            // 524288 floats
    float* bufA = xt + 524288;           // 4194304 floats
    float* bufB = bufA + 4194304;        // 4194304 floats
    float* wt1 = bufB + 4194304;         // 18432
    float* wt2 = wt1 + 18432;            // 147456
    float* wt3 = wt2 + 147456;           // 147456
    float* e2 = wt3 + 147456;            // 8192
    int* idx = (int*)(e2 + 8192);                    // 32768 ints
    unsigned short* flatbf = (unsigned short*)(idx + 32768);  // 4.19M ushorts
    unsigned short* embbf = flatbf + (size_t)N_ * 128;        // 1.05M ushorts

    transpose_x_kernel<<<2048, 256, 0, stream>>>(x, xt);
    wtrans_kernel<<<72, 256, 0, stream>>>(ew1, wt1, 16, 9 * 16 * 128);
    wtrans_kernel<<<576, 256, 0, stream>>>(ew2, wt2, 128, 9 * 128 * 128);
    wtrans_kernel<<<576, 256, 0, stream>>>(dw1, wt3, 128, 9 * 128 * 128);
    enorm2_kernel<<<32, 256, 0, stream>>>(embed, e2);
    cast_bf16_kernel<<<1024, 256, 0, stream>>>(embed, embbf);  // 8192*128/4

    conv3x3_gelu_kernel<16, false><<<2048, 256, 0, stream>>>(xt, wt1, eb1, bufA);
    conv3x3_gelu_kernel<128, true><<<2048, 256, 0, stream>>>(bufA, wt2, eb2,
                                                             flatbf);
    vq_mfma_kernel<<<512, 256, 0, stream>>>(flatbf, embbf, e2, idx);
    gather_kernel<<<4096, 256, 0, stream>>>(embed, idx, bufA);
    conv3x3_gelu_kernel<128, false><<<2048, 256, 0, stream>>>(bufA, wt3, db1,
                                                              bufB);
    dec2_kernel<<<512, 256, 0, stream>>>(bufB, dw2, db2, out);
}

// Round 4
// 333.245 us; speedup vs baseline: 142.6783x; 2.0494x over previous
//
#include <hip/hip_runtime.h>

// Problem constants
constexpr int B_ = 8, H_ = 64, W_ = 64, C0 = 16, D_ = 128, K_ = 8192;
constexpr int N_ = B_ * H_ * W_;  // 32768 pixels

typedef __attribute__((ext_vector_type(8))) short short8;   // 8 bf16
typedef __attribute__((ext_vector_type(4))) float f32x4;    // MFMA C/D

__device__ __forceinline__ float gelu_f(float x) {
    return 0.5f * x * (1.0f + erff(x * 0.70710678118654752440f));
}

__device__ __forceinline__ unsigned short f2bf(float f) {  // RNE f32->bf16
    unsigned u = __float_as_uint(f);
    u += 0x7fffu + ((u >> 16) & 1u);
    return (unsigned short)(u >> 16);
}

// ---------------------------------------------------------------------------
// x NCHW [8,16,64,64] -> xt NHWC [8,64,64,16]
__global__ __launch_bounds__(256) void transpose_x_kernel(
    const float* __restrict__ x, float* __restrict__ xt) {
    int i = blockIdx.x * 256 + threadIdx.x;
    int w = i & 63;
    int h = (i >> 6) & 63;
    int c = (i >> 12) & 15;
    int b = i >> 16;
    xt[(((b << 6) + h) * 64 + w) * 16 + c] = x[i];
}

// w OIHW [co][ci][3][3] -> wt [t][ci][co] fp32 (for the VALU conv1)
__global__ __launch_bounds__(256) void wtrans_kernel(
    const float* __restrict__ w, float* __restrict__ wt, int cin, int total) {
    int i = blockIdx.x * 256 + threadIdx.x;
    if (i >= total) return;
    int co = i & 127;
    int rest = i >> 7;
    int ci = rest % cin;
    int t = rest / cin;
    wt[i] = w[(co * cin + ci) * 9 + t];
}

// w OIHW [co][128][3][3] -> wtb [t][co][ci] bf16 (for MFMA convs)
__global__ __launch_bounds__(256) void wtbf_kernel(
    const float* __restrict__ w, unsigned short* __restrict__ wtb) {
    int i = blockIdx.x * 256 + threadIdx.x;  // 147456
    int ci = i & 127;
    int co = (i >> 7) & 127;
    int t = i >> 14;
    wtb[(t * 128 + co) * 128 + ci] = f2bf(w[(co * 128 + ci) * 9 + t]);
}

// ||embed_k||^2 (fp32, exact)
__global__ __launch_bounds__(256) void enorm2_kernel(
    const float* __restrict__ embed, float* __restrict__ e2) {
    int k = blockIdx.x * 256 + threadIdx.x;
    const float4* e4 = (const float4*)(embed + (size_t)k * 128);
    float s = 0.0f;
#pragma unroll 8
    for (int i = 0; i < 32; ++i) {
        float4 v = e4[i];
        s += v.x * v.x + v.y * v.y + v.z * v.z + v.w * v.w;
    }
    e2[k] = s;
}

// fp32 -> bf16 cast, 4 elems/thread
__global__ __launch_bounds__(256) void cast_bf16_kernel(
    const float* __restrict__ in, unsigned short* __restrict__ out) {
    int i = blockIdx.x * 256 + threadIdx.x;
    float4 v = ((const float4*)in)[i];
    uint2 o;
    o.x = (unsigned)f2bf(v.x) | ((unsigned)f2bf(v.y) << 16);
    o.y = (unsigned)f2bf(v.z) | ((unsigned)f2bf(v.w) << 16);
    ((uint2*)out)[i] = o;
}

// ---------------------------------------------------------------------------
// 3x3 SAME conv (fp32 VALU path), NHWC, fused bias + GELU; used for CIN=16.
template <int CIN, bool OUT_BF16>
__global__ __launch_bounds__(256) void conv3x3_gelu_kernel(
    const float* __restrict__ in, const float* __restrict__ wt,
    const float* __restrict__ bias, void* __restrict__ out_) {
    constexpr int CIN4 = CIN / 4;
    __shared__ __align__(16) float patch[3 * 18 * CIN];
    int blk = blockIdx.x;  // 2048 = 8 * 64 * 4
    int w0 = (blk & 3) * 16;
    int h = (blk >> 2) & 63;
    int b = blk >> 8;

    constexpr int SLOTS = 3 * 18 * CIN4;
    for (int i = threadIdx.x; i < SLOTS; i += 256) {
        int ci4 = i % CIN4;
        int c = (i / CIN4) % 18;
        int r = i / (CIN4 * 18);
        int hh = h - 1 + r, ww = w0 - 1 + c;
        float4 v = make_float4(0.f, 0.f, 0.f, 0.f);
        if ((unsigned)hh < (unsigned)H_ && (unsigned)ww < (unsigned)W_)
            v = ((const float4*)in)[((b * H_ + hh) * W_ + ww) * CIN4 + ci4];
        ((float4*)patch)[(r * 18 + c) * CIN4 + ci4] = v;
    }
    __syncthreads();

    int co = threadIdx.x & 127;
    int ph = threadIdx.x >> 7;
    float bv = bias[co];
    float acc[8];
#pragma unroll
    for (int j = 0; j < 8; ++j) acc[j] = bv;

#pragma unroll
    for (int ky = 0; ky < 3; ++ky)
#pragma unroll
        for (int kx = 0; kx < 3; ++kx) {
            const float* wrow = wt + ((ky * 3 + kx) * CIN) * 128 + co;
            const float* prow = &patch[(ky * 18 + kx + ph * 8) * CIN];
#pragma unroll 1
            for (int ci = 0; ci < CIN; ci += 4) {
                float wa = wrow[(ci + 0) * 128];
                float wb = wrow[(ci + 1) * 128];
                float wc = wrow[(ci + 2) * 128];
                float wd = wrow[(ci + 3) * 128];
#pragma unroll
                for (int j = 0; j < 8; ++j) {
                    float4 p = *(const float4*)&prow[j * CIN + ci];
                    acc[j] += p.x * wa + p.y * wb + p.z * wc + p.w * wd;
                }
            }
        }

    int pixbase = (b * H_ + h) * W_ + w0 + ph * 8;
#pragma unroll
    for (int j = 0; j < 8; ++j) {
        float g = gelu_f(acc[j]);
        if (OUT_BF16)
            ((unsigned short*)out_)[(size_t)(pixbase + j) * 128 + co] = f2bf(g);
        else
            ((float*)out_)[(size_t)(pixbase + j) * 128 + co] = g;
    }
}

// ---------------------------------------------------------------------------
// 3x3 SAME conv via bf16 MFMA: 9 shifted K=128 GEMMs.
// Block = 128 px (2 image rows) x 128 cout; 4 waves, each 64px x 64co.
// Per tap: stage shifted/zero-masked A (32KB) + weight tile B (32KB) into
// padded LDS (stride 136 shorts -> b128 frag reads conflict-free), 4 k-steps.
template <bool OUT_BF16>
__global__ __launch_bounds__(256, 2) void conv3x3_mfma_kernel(
    const unsigned short* __restrict__ in,   // NHWC [B,64,64,128] bf16
    const unsigned short* __restrict__ wtb,  // [9][co][ci] bf16
    const float* __restrict__ bias,          // [128]
    void* __restrict__ out_) {               // NHWC fp32 or bf16
    constexpr int LDA = 136;
    __shared__ unsigned short As[128 * LDA];  // 34816 B
    __shared__ unsigned short Bs[128 * LDA];  // 34816 B
    int tid = threadIdx.x;
    int w4 = tid >> 6, lane = tid & 63;
    int r = lane & 15, q = lane >> 4;
    int mh = w4 & 1, nh = w4 >> 1;
    int b = blockIdx.x >> 5;
    int h0 = (blockIdx.x & 31) * 2;

    f32x4 acc[4][4];
#pragma unroll
    for (int ms = 0; ms < 4; ++ms)
#pragma unroll
        for (int ns = 0; ns < 4; ++ns) acc[ms][ns] = (f32x4){0.f, 0.f, 0.f, 0.f};

    for (int t = 0; t < 9; ++t) {
        int dy = t / 3 - 1, dx = t % 3 - 1;
        __syncthreads();  // previous tap's frag reads complete
        // stage A: 128 px x 128 ci, shifted, zero at image edges
#pragma unroll
        for (int j = 0; j < 8; ++j) {
            int slot = tid + j * 256;  // px*16 + c16
            int px = slot >> 4, c16 = slot & 15;
            int hh = h0 + (px >> 6) + dy;
            int ww = (px & 63) + dx;
            float4 v = make_float4(0.f, 0.f, 0.f, 0.f);
            if ((unsigned)hh < 64u && (unsigned)ww < 64u)
                v = ((const float4*)in)[((size_t)((b * 64 + hh) * 64 + ww)) * 16 +
                                        c16];
            *(float4*)(As + px * LDA + c16 * 8) = v;
        }
        // stage B: this tap's 128co x 128ci
        const float4* wsrc = (const float4*)(wtb + t * 16384);
#pragma unroll
        for (int j = 0; j < 8; ++j) {
            int slot = tid + j * 256;
            int co = slot >> 4, c16 = slot & 15;
            *(float4*)(Bs + co * LDA + c16 * 8) = wsrc[slot];
        }
        __syncthreads();
#pragma unroll
        for (int k = 0; k < 4; ++k) {
            short8 af[4], bf[4];
#pragma unroll
            for (int ms = 0; ms < 4; ++ms)
                af[ms] = *(const short8*)(As + (mh * 64 + ms * 16 + r) * LDA +
                                          k * 32 + q * 8);
#pragma unroll
            for (int ns = 0; ns < 4; ++ns)
                bf[ns] = *(const short8*)(Bs + (nh * 64 + ns * 16 + r) * LDA +
                                          k * 32 + q * 8);
#pragma unroll
            for (int ms = 0; ms < 4; ++ms)
#pragma unroll
                for (int ns = 0; ns < 4; ++ns)
                    acc[ms][ns] = __builtin_amdgcn_mfma_f32_16x16x32_bf16(
                        af[ms], bf[ns], acc[ms][ns], 0, 0, 0);
        }
    }

    // epilogue: bias + GELU + store (C layout: row=q*4+rg -> pixel, col=r -> co)
#pragma unroll
    for (int ns = 0; ns < 4; ++ns) {
        int co = nh * 64 + ns * 16 + r;
        float bv = bias[co];
#pragma unroll
        for (int ms = 0; ms < 4; ++ms)
#pragma unroll
            for (int rg = 0; rg < 4; ++rg) {
                int pl = mh * 64 + ms * 16 + q * 4 + rg;
                int pix = (b * 64 + h0 + (pl >> 6)) * 64 + (pl & 63);
                float g = gelu_f(acc[ms][ns][rg] + bv);
                if (OUT_BF16)
                    ((unsigned short*)out_)[(size_t)pix * 128 + co] = f2bf(g);
                else
                    ((float*)out_)[(size_t)pix * 128 + co] = g;
            }
    }
}

// ---------------------------------------------------------------------------
// VQ via bf16 MFMA (unchanged from round 3).
__global__ __launch_bounds__(256, 2) void vq_mfma_kernel(
    const unsigned short* __restrict__ flatbf, const unsigned short* __restrict__ embbf,
    const float* __restrict__ e2, int* __restrict__ out_idx) {
    constexpr int LDB = 136;
    __shared__ unsigned short Bs[256 * LDB];  // 68 KB
    __shared__ float e2s[256];
    int tid = threadIdx.x;
    int w = tid >> 6, lane = tid & 63;
    int r = lane & 15, q = lane >> 4;
    int m0 = blockIdx.x * 64;

#pragma unroll
    for (int j = 0; j < 4; ++j) {
        int row = j * 16 + (tid >> 4), col = tid & 15;
        float4 v = *(const float4*)(flatbf + (size_t)(m0 + row) * 128 + col * 8);
        *(float4*)(Bs + row * LDB + col * 8) = v;
    }
    __syncthreads();
    short8 afr[4][4];
#pragma unroll
    for (int ms = 0; ms < 4; ++ms)
#pragma unroll
        for (int k = 0; k < 4; ++k)
            afr[ms][k] = *(const short8*)(Bs + (ms * 16 + r) * LDB + k * 32 + q * 8);
    __syncthreads();

    float best[4][4];
    int bidx[4][4];
#pragma unroll
    for (int ms = 0; ms < 4; ++ms)
#pragma unroll
        for (int rg = 0; rg < 4; ++rg) {
            best[ms][rg] = 3.4e38f;
            bidx[ms][rg] = 0;
        }

    for (int it = 0; it < 32; ++it) {
        int cbase = it << 8;
#pragma unroll 4
        for (int j = 0; j < 16; ++j) {
            int row = j * 16 + (tid >> 4), col = tid & 15;
            float4 v = *(const float4*)(embbf + (size_t)(cbase + row) * 128 + col * 8);
            *(float4*)(Bs + row * LDB + col * 8) = v;
        }
        e2s[tid] = e2[cbase + tid];
        __syncthreads();

        f32x4 acc[4][4];
#pragma unroll
        for (int ms = 0; ms < 4; ++ms)
#pragma unroll
            for (int ns = 0; ns < 4; ++ns) acc[ms][ns] = (f32x4){0.f, 0.f, 0.f, 0.f};

#pragma unroll
        for (int k = 0; k < 4; ++k) {
            short8 bfr[4];
#pragma unroll
            for (int ns = 0; ns < 4; ++ns)
                bfr[ns] = *(const short8*)(Bs + (w * 64 + ns * 16 + r) * LDB +
                                           k * 32 + q * 8);
#pragma unroll
            for (int ms = 0; ms < 4; ++ms)
#pragma unroll
                for (int ns = 0; ns < 4; ++ns)
                    acc[ms][ns] = __builtin_amdgcn_mfma_f32_16x16x32_bf16(
                        afr[ms][k], bfr[ns], acc[ms][ns], 0, 0, 0);
        }

#pragma unroll
        for (int ns = 0; ns < 4; ++ns) {
            float e2v = e2s[w * 64 + ns * 16 + r];
            int code = cbase + w * 64 + ns * 16 + r;
#pragma unroll
            for (int ms = 0; ms < 4; ++ms)
#pragma unroll
                for (int rg = 0; rg < 4; ++rg) {
                    float s = fmaf(-2.0f, acc[ms][ns][rg], e2v);
                    if (s < best[ms][rg]) {
                        best[ms][rg] = s;
                        bidx[ms][rg] = code;
                    }
                }
        }
        __syncthreads();
    }

    float* sred = (float*)Bs;
    int* ired = (int*)(Bs + 8320);
    int cand = w * 16 + r;
#pragma unroll
    for (int ms = 0; ms < 4; ++ms)
#pragma unroll
        for (int rg = 0; rg < 4; ++rg) {
            int pixel = ms * 16 + q * 4 + rg;
            sred[pixel * 65 + cand] = best[ms][rg];
            ired[pixel * 65 + cand] = bidx[ms][rg];
        }
    __syncthreads();
    if (tid < 64) {
        float bs = sred[tid * 65];
        int bi = ired[tid * 65];
        for (int c = 1; c < 64; ++c) {
            float s = sred[tid * 65 + c];
            int i2 = ired[tid * 65 + c];
            if (s < bs || (s == bs && i2 < bi)) {
                bs = s;
                bi = i2;
            }
        }
        out_idx[m0 + tid] = bi;
    }
}

// ---------------------------------------------------------------------------
// gather codebook rows as bf16 (feeds MFMA decoder conv)
__global__ __launch_bounds__(256) void gather_bf16_kernel(
    const unsigned short* __restrict__ embbf, const int* __restrict__ idx,
    unsigned short* __restrict__ qbf) {
    int n = blockIdx.x * 16 + (threadIdx.x >> 4);
    int c16 = threadIdx.x & 15;
    int k = idx[n];
    ((float4*)qbf)[(size_t)n * 16 + c16] = ((const float4*)embbf)[(size_t)k * 16 + c16];
}

// 1x1 conv (128->16) + sigmoid, NHWC in -> NCHW out
__global__ __launch_bounds__(256) void dec2_kernel(
    const float* __restrict__ y, const float* __restrict__ w2,
    const float* __restrict__ b2, float* __restrict__ out) {
    __shared__ float ys[64 * 130];
    __shared__ float ws[16 * 128];
    int blk = blockIdx.x;  // 512 = B*H
    int h = blk & 63;
    int b = blk >> 6;
    const float* yrow = y + (size_t)((b * H_ + h) * W_) * 128;
    for (int i = threadIdx.x; i < 64 * 64; i += 256) {
        int w = i >> 6, dh = i & 63;
        *(float2*)&ys[w * 130 + dh * 2] = *(const float2*)&yrow[w * 128 + dh * 2];
    }
    for (int i = threadIdx.x; i < 2048; i += 256) ws[i] = w2[i];
    __syncthreads();

    int w = threadIdx.x & 63;
    int c0 = (threadIdx.x >> 6) * 4;
    float acc[4] = {b2[c0], b2[c0 + 1], b2[c0 + 2], b2[c0 + 3]};
#pragma unroll 1
    for (int ci = 0; ci < 128; ci += 2) {
        float2 yv = *(const float2*)&ys[w * 130 + ci];
#pragma unroll
        for (int jc = 0; jc < 4; ++jc) {
            float2 wv = *(const float2*)&ws[(c0 + jc) * 128 + ci];
            acc[jc] += yv.x * wv.x + yv.y * wv.y;
        }
    }
#pragma unroll
    for (int jc = 0; jc < 4; ++jc) {
        float v = 1.0f / (1.0f + expf(-acc[jc]));
        out[(((size_t)b * 16 + c0 + jc) * H_ + h) * W_ + w] = v;
    }
}

// ---------------------------------------------------------------------------
extern "C" void kernel_launch(void* const* d_in, const int* in_sizes, int n_in,
                              void* d_out, int out_size, void* d_ws,
                              size_t ws_size, hipStream_t stream) {
    const float* x = (const float*)d_in[0];
    const float* ew1 = (const float*)d_in[1];
    const float* eb1 = (const float*)d_in[2];
    const float* ew2 = (const float*)d_in[3];
    const float* eb2 = (const float*)d_in[4];
    const float* embed = (const float*)d_in[5];
    const float* dw1 = (const float*)d_in[6];
    const float* db1 = (const float*)d_in[7];
    const float* dw2 = (const float*)d_in[8];
    const float* db2 = (const float*)d_in[9];
    float* out = (float*)d_out;

    float* xt = (float*)d_ws;                       // 524288 f
    float* wt1 = xt + 524288;                       // 18432 f
    float* e2 = wt1 + 18432;                        // 8192 f
    float* bufB = e2 + 8192;                        // 4194304 f (dec conv1 out)
    int* idx = (int*)(bufB + 4194304);              // 32768 i
    unsigned short* wtbf2 = (unsigned short*)(idx + 32768);  // 147456 us
    unsigned short* wtbf3 = wtbf2 + 147456;                  // 147456 us
    unsigned short* embbf = wtbf3 + 147456;                  // 1048576 us
    unsigned short* abf = embbf + 1048576;                   // 4194304 us
    unsigned short* flatbf = abf + 4194304;                  // 4194304 us
    unsigned short* qbf = flatbf + 4194304;                  // 4194304 us

    transpose_x_kernel<<<2048, 256, 0, stream>>>(x, xt);
    wtrans_kernel<<<72, 256, 0, stream>>>(ew1, wt1, 16, 9 * 16 * 128);
    wtbf_kernel<<<576, 256, 0, stream>>>(ew2, wtbf2);
    wtbf_kernel<<<576, 256, 0, stream>>>(dw1, wtbf3);
    enorm2_kernel<<<32, 256, 0, stream>>>(embed, e2);
    cast_bf16_kernel<<<1024, 256, 0, stream>>>(embed, embbf);

    conv3x3_gelu_kernel<16, true><<<2048, 256, 0, stream>>>(xt, wt1, eb1, abf);
    conv3x3_mfma_kernel<true><<<256, 256, 0, stream>>>(abf, wtbf2, eb2, flatbf);
    vq_mfma_kernel<<<512, 256, 0, stream>>>(flatbf, embbf, e2, idx);
    gather_bf16_kernel<<<2048, 256, 0, stream>>>(embbf, idx, qbf);
    conv3x3_mfma_kernel<false><<<256, 256, 0, stream>>>(qbf, wtbf3, db1, bufB);
    dec2_kernel<<<512, 256, 0, stream>>>(bufB, dw2, db2, out);
}

// Round 5
// 298.917 us; speedup vs baseline: 159.0634x; 1.1148x over previous
//
#include <hip/hip_runtime.h>

// Problem constants
constexpr int B_ = 8, H_ = 64, W_ = 64, C0 = 16, D_ = 128, K_ = 8192;
constexpr int N_ = B_ * H_ * W_;  // 32768 pixels

typedef __attribute__((ext_vector_type(8))) short short8;  // 8 bf16
typedef __attribute__((ext_vector_type(4))) float f32x4;   // MFMA C/D

__device__ __forceinline__ float gelu_f(float x) {
    return 0.5f * x * (1.0f + erff(x * 0.70710678118654752440f));
}

__device__ __forceinline__ unsigned short f2bf(float f) {  // RNE f32->bf16
    unsigned u = __float_as_uint(f);
    u += 0x7fffu + ((u >> 16) & 1u);
    return (unsigned short)(u >> 16);
}

// ---------------------------------------------------------------------------
// One fused prep kernel (block-range switched):
//  A [0,2048):      x NCHW f32 -> xtbf NHWC bf16
//  B [2048,2624):   ew2 OIHW -> wtbf2 [t][co][ci] bf16
//  C [2624,3200):   dw1 OIHW -> wtbf3 [t][co][ci] bf16
//  D [3200,3232):   e2[k] = ||embed_k||^2 (fp32)
//  E [3232,4256):   embed f32 -> embbf bf16
//  F [4256,4336):   ew1 OIHW -> wtb1b [co][kk=t*16+ci, pad 160] bf16
__global__ __launch_bounds__(256) void prep_kernel(
    const float* __restrict__ x, const float* __restrict__ ew1,
    const float* __restrict__ ew2, const float* __restrict__ dw1,
    const float* __restrict__ embed, unsigned short* __restrict__ xtbf,
    unsigned short* __restrict__ wtbf2, unsigned short* __restrict__ wtbf3,
    float* __restrict__ e2, unsigned short* __restrict__ embbf,
    unsigned short* __restrict__ wtb1b) {
    int blk = blockIdx.x;
    int tid = threadIdx.x;
    if (blk < 2048) {  // A: xtbf (out-contiguous)
        int j = blk * 256 + tid;
        int c = j & 15, w = (j >> 4) & 63, h = (j >> 10) & 63, b = j >> 16;
        xtbf[j] = f2bf(x[(((b << 4) + c) << 12) + (h << 6) + w]);
    } else if (blk < 3200) {  // B/C: 3x3 128-ch weights -> [t][co][ci] bf16
        const float* src = (blk < 2624) ? ew2 : dw1;
        unsigned short* dst = (blk < 2624) ? wtbf2 : wtbf3;
        int i = (blk - ((blk < 2624) ? 2048 : 2624)) * 256 + tid;
        int ci = i & 127, co = (i >> 7) & 127, t = i >> 14;
        dst[i] = f2bf(src[(co * 128 + ci) * 9 + t]);
    } else if (blk < 3232) {  // D: e2
        int k = (blk - 3200) * 256 + tid;
        const float4* e4 = (const float4*)(embed + (size_t)k * 128);
        float s = 0.0f;
#pragma unroll 8
        for (int i = 0; i < 32; ++i) {
            float4 v = e4[i];
            s += v.x * v.x + v.y * v.y + v.z * v.z + v.w * v.w;
        }
        e2[k] = s;
    } else if (blk < 4256) {  // E: embbf
        int i = (blk - 3232) * 256 + tid;
        float4 v = ((const float4*)embed)[i];
        uint2 o;
        o.x = (unsigned)f2bf(v.x) | ((unsigned)f2bf(v.y) << 16);
        o.y = (unsigned)f2bf(v.z) | ((unsigned)f2bf(v.w) << 16);
        ((uint2*)embbf)[i] = o;
    } else {  // F: wtb1b [128 co][160 kk]
        int i = (blk - 4256) * 256 + tid;  // < 20480
        int co = i / 160, kk = i % 160;
        float v = 0.0f;
        if (kk < 144) {
            int t = kk >> 4, ci = kk & 15;
            v = ew1[(co * 16 + ci) * 9 + t];
        }
        wtb1b[i] = f2bf(v);
    }
}

// ---------------------------------------------------------------------------
// conv1: 16->128 3x3 + GELU via MFMA, K=160 (9 taps x 16 ci, zero-padded).
// Block = 1 output row (64 px) x 128 co; 4 waves, each 64px x 32co.
// A tile (im2col) in LDS (stride 168 shorts, bank-even); B direct from L2.
__global__ __launch_bounds__(256, 2) void conv1_mfma_kernel(
    const unsigned short* __restrict__ xtbf,   // NHWC [B,64,64,16] bf16
    const unsigned short* __restrict__ wtb1b,  // [128][160] bf16
    const float* __restrict__ bias,            // [128]
    unsigned short* __restrict__ out) {        // NHWC [B,64,64,128] bf16
    constexpr int LDA = 168;
    __shared__ __align__(16) unsigned short As[64 * LDA];  // 21504 B
    int tid = threadIdx.x;
    int wv = tid >> 6, lane = tid & 63;
    int r = lane & 15, q = lane >> 4;
    int h0 = blockIdx.x & 63, b = blockIdx.x >> 6;

    // stage im2col A: slots [0,1152) = px*18 + t*2 + half; [1152,1280) zeros
#pragma unroll
    for (int j = 0; j < 5; ++j) {
        int s = tid + j * 256;
        if (s < 1152) {
            int px = s / 18, rem = s % 18;
            int t = rem >> 1, half = rem & 1;
            int hh = h0 + t / 3 - 1, ww = px + t % 3 - 1;
            float4 v = make_float4(0.f, 0.f, 0.f, 0.f);
            if ((unsigned)hh < 64u && (unsigned)ww < 64u)
                v = *(const float4*)(xtbf + (((b * 64 + hh) * 64 + ww) << 4) +
                                     half * 8);
            *(float4*)(As + px * LDA + t * 16 + half * 8) = v;
        } else {
            int z = s - 1152;  // < 128
            int px = z >> 1, half = z & 1;
            *(float4*)(As + px * LDA + 144 + half * 8) =
                make_float4(0.f, 0.f, 0.f, 0.f);
        }
    }
    __syncthreads();

    f32x4 acc[4][2];
#pragma unroll
    for (int ms = 0; ms < 4; ++ms)
#pragma unroll
        for (int ns = 0; ns < 2; ++ns) acc[ms][ns] = (f32x4){0.f, 0.f, 0.f, 0.f};

#pragma unroll
    for (int k = 0; k < 5; ++k) {
        short8 af[4], bf[2];
#pragma unroll
        for (int ms = 0; ms < 4; ++ms)
            af[ms] = *(const short8*)(As + (ms * 16 + r) * LDA + k * 32 + q * 8);
#pragma unroll
        for (int ns = 0; ns < 2; ++ns) {
            int co = wv * 32 + ns * 16 + r;
            bf[ns] = *(const short8*)(wtb1b + co * 160 + k * 32 + q * 8);
        }
#pragma unroll
        for (int ms = 0; ms < 4; ++ms)
#pragma unroll
            for (int ns = 0; ns < 2; ++ns)
                acc[ms][ns] = __builtin_amdgcn_mfma_f32_16x16x32_bf16(
                    af[ms], bf[ns], acc[ms][ns], 0, 0, 0);
    }

#pragma unroll
    for (int ns = 0; ns < 2; ++ns) {
        int co = wv * 32 + ns * 16 + r;
        float bv = bias[co];
#pragma unroll
        for (int ms = 0; ms < 4; ++ms)
#pragma unroll
            for (int rg = 0; rg < 4; ++rg) {
                int px = ms * 16 + q * 4 + rg;
                int pix = (b * 64 + h0) * 64 + px;
                out[(size_t)pix * 128 + co] =
                    f2bf(gelu_f(acc[ms][ns][rg] + bv));
            }
    }
}

// ---------------------------------------------------------------------------
// 3x3 128->128 conv + GELU via MFMA. Block = 1 output row (64px) x 128 co;
// 4 waves, each 64px x 32co. 3-row halo staged ONCE (stride 136 shorts);
// weights direct global->VGPR (L2-resident); no per-tap barriers.
template <bool OUT_BF16>
__global__ __launch_bounds__(256, 2) void conv3x3_mfma_kernel(
    const unsigned short* __restrict__ in,   // NHWC [B,64,64,128] bf16
    const unsigned short* __restrict__ wtb,  // [9][co][ci] bf16
    const float* __restrict__ bias,          // [128]
    void* __restrict__ out_) {               // NHWC fp32 or bf16
    constexpr int LDC = 136;                 // shorts per col slot
    __shared__ __align__(16) unsigned short As[3 * 66 * LDC];  // 53856 B
    int tid = threadIdx.x;
    int wv = tid >> 6, lane = tid & 63;
    int r = lane & 15, q = lane >> 4;
    int h0 = blockIdx.x & 63, b = blockIdx.x >> 6;

    // stage halo: 3 rows x 66 cols x 128 ci (16 chunks of 16B per col)
    for (int j = 0; j < 13; ++j) {
        int s = tid + j * 256;
        if (s < 3168) {
            int col = s >> 4, chunk = s & 15;
            int ry = col / 66, cx = col % 66;
            int hh = h0 - 1 + ry, ww = cx - 1;
            float4 v = make_float4(0.f, 0.f, 0.f, 0.f);
            if ((unsigned)hh < 64u && (unsigned)ww < 64u)
                v = *(const float4*)(in + ((size_t)((b * 64 + hh) * 64 + ww))
                                              * 128 + chunk * 8);
            *(float4*)(As + col * LDC + chunk * 8) = v;
        }
    }
    __syncthreads();

    f32x4 acc[4][2];
#pragma unroll
    for (int ms = 0; ms < 4; ++ms)
#pragma unroll
        for (int ns = 0; ns < 2; ++ns) acc[ms][ns] = (f32x4){0.f, 0.f, 0.f, 0.f};

    for (int t = 0; t < 9; ++t) {
        int dy = t / 3, dx = t % 3;  // 0..2 == shift -1..+1 (col = px+dx)
        const unsigned short* wsrc = wtb + t * 16384;
#pragma unroll
        for (int k = 0; k < 4; ++k) {
            short8 af[4], bf[2];
#pragma unroll
            for (int ms = 0; ms < 4; ++ms) {
                int col = dy * 66 + ms * 16 + r + dx;
                af[ms] = *(const short8*)(As + col * LDC + k * 32 + q * 8);
            }
#pragma unroll
            for (int ns = 0; ns < 2; ++ns) {
                int co = wv * 32 + ns * 16 + r;
                bf[ns] = *(const short8*)(wsrc + co * 128 + k * 32 + q * 8);
            }
#pragma unroll
            for (int ms = 0; ms < 4; ++ms)
#pragma unroll
                for (int ns = 0; ns < 2; ++ns)
                    acc[ms][ns] = __builtin_amdgcn_mfma_f32_16x16x32_bf16(
                        af[ms], bf[ns], acc[ms][ns], 0, 0, 0);
        }
    }

#pragma unroll
    for (int ns = 0; ns < 2; ++ns) {
        int co = wv * 32 + ns * 16 + r;
        float bv = bias[co];
#pragma unroll
        for (int ms = 0; ms < 4; ++ms)
#pragma unroll
            for (int rg = 0; rg < 4; ++rg) {
                int px = ms * 16 + q * 4 + rg;
                int pix = (b * 64 + h0) * 64 + px;
                float g = gelu_f(acc[ms][ns][rg] + bv);
                if (OUT_BF16)
                    ((unsigned short*)out_)[(size_t)pix * 128 + co] = f2bf(g);
                else
                    ((float*)out_)[(size_t)pix * 128 + co] = g;
            }
    }
}

// ---------------------------------------------------------------------------
// VQ argmin via bf16 MFMA, B (codes) streamed global->VGPR (L2-resident).
// Block = 64 pixels x all 8192 codes; 4 waves each own 64 codes/iter.
// acc init = -e2/2 so MFMA yields f.e - e2/2 -> argMAX. Low 7 mantissa bits
// of each score carry key=(127-(it*4+ns)): single v_max_f32 keeps (score,key)
// jointly; larger key == smaller code index on ties (positive scores).
__global__ __launch_bounds__(256, 2) void vq_mfma_kernel(
    const unsigned short* __restrict__ flatbf,  // [N][128] bf16
    const unsigned short* __restrict__ embbf,   // [K][128] bf16
    const float* __restrict__ e2,               // [K] fp32
    int* __restrict__ out_idx) {                // [N]
    constexpr int LDA = 136;
    __shared__ __align__(16) unsigned short SH[16640];  // 33280 B (stage+merge)
    int tid = threadIdx.x;
    int wv = tid >> 6, lane = tid & 63;
    int r = lane & 15, q = lane >> 4;
    int m0 = blockIdx.x * 64;

    // stage A (64 px x 128 d) and preload frags to registers
#pragma unroll
    for (int j = 0; j < 4; ++j) {
        int row = j * 16 + (tid >> 4), col = tid & 15;
        float4 v = *(const float4*)(flatbf + (size_t)(m0 + row) * 128 + col * 8);
        *(float4*)(SH + row * LDA + col * 8) = v;
    }
    __syncthreads();
    short8 afr[4][4];  // [ms][k]
#pragma unroll
    for (int ms = 0; ms < 4; ++ms)
#pragma unroll
        for (int k = 0; k < 4; ++k)
            afr[ms][k] = *(const short8*)(SH + (ms * 16 + r) * LDA + k * 32 + q * 8);
    __syncthreads();  // all waves done reading A; SH reusable for merge

    float best[4][4];
#pragma unroll
    for (int ms = 0; ms < 4; ++ms)
#pragma unroll
        for (int rg = 0; rg < 4; ++rg) best[ms][rg] = -3.4e38f;

    const unsigned short* bp = embbf + (size_t)(wv * 64 + r) * 128 + q * 8;
    const float* e2p = e2 + wv * 64 + r;

    for (int it = 0; it < 32; ++it) {
        // e2 for this wave's 4 code slots
        float e2v[4];
#pragma unroll
        for (int ns = 0; ns < 4; ++ns) e2v[ns] = e2p[it * 256 + ns * 16];

        f32x4 acc[4][4];  // [ms][ns], init -e2/2
#pragma unroll
        for (int ns = 0; ns < 4; ++ns) {
            float v = -0.5f * e2v[ns];
#pragma unroll
            for (int ms = 0; ms < 4; ++ms) acc[ms][ns] = (f32x4){v, v, v, v};
        }

#pragma unroll
        for (int k = 0; k < 4; ++k) {
            short8 bfr[4];
#pragma unroll
            for (int ns = 0; ns < 4; ++ns)
                bfr[ns] = *(const short8*)(bp + (size_t)it * 32768 + ns * 2048 +
                                           k * 32);
#pragma unroll
            for (int ms = 0; ms < 4; ++ms)
#pragma unroll
                for (int ns = 0; ns < 4; ++ns)
                    acc[ms][ns] = __builtin_amdgcn_mfma_f32_16x16x32_bf16(
                        afr[ms][k], bfr[ns], acc[ms][ns], 0, 0, 0);
        }

        // pack key into low 7 mantissa bits, running max
#pragma unroll
        for (int ns = 0; ns < 4; ++ns) {
            unsigned key = 127u - (unsigned)(it * 4 + ns);
#pragma unroll
            for (int ms = 0; ms < 4; ++ms)
#pragma unroll
                for (int rg = 0; rg < 4; ++rg) {
                    unsigned u = (__float_as_uint(acc[ms][ns][rg]) & 0xFFFFFF80u)
                                 | key;
                    best[ms][rg] = fmaxf(best[ms][rg], __uint_as_float(u));
                }
        }
    }

    // decode (it,ns) from key; merge 64 candidates/pixel via LDS
    float* sred = (float*)SH;          // [64][65] floats (16640 B)
    int* ired = (int*)SH + 4160;       // [64][65] ints
    int cand = wv * 16 + r;
#pragma unroll
    for (int ms = 0; ms < 4; ++ms)
#pragma unroll
        for (int rg = 0; rg < 4; ++rg) {
            unsigned bits = __float_as_uint(best[ms][rg]);
            unsigned keyinv = 127u - (bits & 127u);
            int code = (int)(keyinv >> 2) * 256 + wv * 64 +
                       (int)(keyinv & 3u) * 16 + r;
            int pixel = ms * 16 + q * 4 + rg;
            sred[pixel * 65 + cand] = best[ms][rg];
            ired[pixel * 65 + cand] = code;
        }
    __syncthreads();
    if (tid < 64) {
        float bs = sred[tid * 65];
        int bi = ired[tid * 65];
        for (int c = 1; c < 64; ++c) {
            float s = sred[tid * 65 + c];
            int i2 = ired[tid * 65 + c];
            if (s > bs || (s == bs && i2 < bi)) {
                bs = s;
                bi = i2;
            }
        }
        out_idx[m0 + tid] = bi;
    }
}

// ---------------------------------------------------------------------------
__global__ __launch_bounds__(256) void gather_bf16_kernel(
    const unsigned short* __restrict__ embbf, const int* __restrict__ idx,
    unsigned short* __restrict__ qbf) {
    int n = blockIdx.x * 16 + (threadIdx.x >> 4);
    int c16 = threadIdx.x & 15;
    int k = idx[n];
    ((float4*)qbf)[(size_t)n * 16 + c16] =
        ((const float4*)embbf)[(size_t)k * 16 + c16];
}

// 1x1 conv (128->16) + sigmoid, NHWC fp32 in -> NCHW fp32 out
__global__ __launch_bounds__(256) void dec2_kernel(
    const float* __restrict__ y, const float* __restrict__ w2,
    const float* __restrict__ b2, float* __restrict__ out) {
    __shared__ float ys[64 * 130];
    __shared__ float ws[16 * 128];
    int blk = blockIdx.x;  // 512 = B*H
    int h = blk & 63;
    int b = blk >> 6;
    const float* yrow = y + (size_t)((b * H_ + h) * W_) * 128;
    for (int i = threadIdx.x; i < 64 * 64; i += 256) {
        int w = i >> 6, dh = i & 63;
        *(float2*)&ys[w * 130 + dh * 2] = *(const float2*)&yrow[w * 128 + dh * 2];
    }
    for (int i = threadIdx.x; i < 2048; i += 256) ws[i] = w2[i];
    __syncthreads();

    int w = threadIdx.x & 63;
    int c0 = (threadIdx.x >> 6) * 4;
    float acc[4] = {b2[c0], b2[c0 + 1], b2[c0 + 2], b2[c0 + 3]};
#pragma unroll 1
    for (int ci = 0; ci < 128; ci += 2) {
        float2 yv = *(const float2*)&ys[w * 130 + ci];
#pragma unroll
        for (int jc = 0; jc < 4; ++jc) {
            float2 wv = *(const float2*)&ws[(c0 + jc) * 128 + ci];
            acc[jc] += yv.x * wv.x + yv.y * wv.y;
        }
    }
#pragma unroll
    for (int jc = 0; jc < 4; ++jc) {
        float v = 1.0f / (1.0f + expf(-acc[jc]));
        out[(((size_t)b * 16 + c0 + jc) * H_ + h) * W_ + w] = v;
    }
}

// ---------------------------------------------------------------------------
extern "C" void kernel_launch(void* const* d_in, const int* in_sizes, int n_in,
                              void* d_out, int out_size, void* d_ws,
                              size_t ws_size, hipStream_t stream) {
    const float* x = (const float*)d_in[0];
    const float* ew1 = (const float*)d_in[1];
    const float* eb1 = (const float*)d_in[2];
    const float* ew2 = (const float*)d_in[3];
    const float* eb2 = (const float*)d_in[4];
    const float* embed = (const float*)d_in[5];
    const float* dw1 = (const float*)d_in[6];
    const float* db1 = (const float*)d_in[7];
    const float* dw2 = (const float*)d_in[8];
    const float* db2 = (const float*)d_in[9];
    float* out = (float*)d_out;

    float* e2 = (float*)d_ws;                         // 8192 f
    float* dec1out = e2 + 8192;                       // 4194304 f
    int* idx = (int*)(dec1out + 4194304);             // 32768 i
    unsigned short* xtbf = (unsigned short*)(idx + 32768);  // 524288 us
    unsigned short* wtb1b = xtbf + 524288;                  // 20480 us
    unsigned short* wtbf2 = wtb1b + 20480;                  // 147456 us
    unsigned short* wtbf3 = wtbf2 + 147456;                 // 147456 us
    unsigned short* embbf = wtbf3 + 147456;                 // 1048576 us
    unsigned short* abf = embbf + 1048576;                  // 4194304 us
    unsigned short* flatbf = abf + 4194304;                 // 4194304 us
    unsigned short* qbf = flatbf + 4194304;                 // 4194304 us

    prep_kernel<<<4336, 256, 0, stream>>>(x, ew1, ew2, dw1, embed, xtbf, wtbf2,
                                          wtbf3, e2, embbf, wtb1b);
    conv1_mfma_kernel<<<512, 256, 0, stream>>>(xtbf, wtb1b, eb1, abf);
    conv3x3_mfma_kernel<true><<<512, 256, 0, stream>>>(abf, wtbf2, eb2, flatbf);
    vq_mfma_kernel<<<512, 256, 0, stream>>>(flatbf, embbf, e2, idx);
    gather_bf16_kernel<<<2048, 256, 0, stream>>>(embbf, idx, qbf);
    conv3x3_mfma_kernel<false><<<512, 256, 0, stream>>>(qbf, wtbf3, db1,
                                                        dec1out);
    dec2_kernel<<<512, 256, 0, stream>>>(dec1out, dw2, db2, out);
}